// Round 9
// baseline (743.340 us; speedup 1.0000x reference)
//
#include <hip/hip_runtime.h>
#include <stdint.h>

// Problem dims
#define MROWS 32768   // B*T
#define TSEQ  1024
#define BBATCH 32
#define INDIM 1536
#define DDIM  768
#define NCAT  2304    // un_emb (768) + pw_x (768) + pw_y (768)

typedef short short8 __attribute__((ext_vector_type(8)));
typedef short short4v __attribute__((ext_vector_type(4)));
typedef float f32x4  __attribute__((ext_vector_type(4)));

__device__ __forceinline__ float b2f(ushort u) {
    union { uint32_t u; float f; } x; x.u = ((uint32_t)u) << 16; return x.f;
}
__device__ __forceinline__ ushort f2b(float f) {
    union { float f; uint32_t u; } x; x.f = f;
    uint32_t r = x.u + 0x7fffu + ((x.u >> 16) & 1u);
    return (ushort)(r >> 16);
}

__device__ __forceinline__ void cvt4(const float* __restrict__ in, ushort* __restrict__ out, int i) {
    float4 v = ((const float4*)in)[i];
    ushort4 o;
    o.x = f2b(v.x); o.y = f2b(v.y); o.z = f2b(v.z); o.w = f2b(v.w);
    ((ushort4*)out)[i] = o;
}

// ---------------- weight conversions + bias concat + accumulator zeroing (x handled in GEMM1) ----
#define C0 589824    // fc1_w -> W1
#define C1 884736    // fc2_w -> W2
#define C2 1032192   // un_emb_w -> W3[0]
#define C3 1179648   // pw_x_w -> W3[1]
#define C4 1327104   // pw_y_w -> W3[2]
#define C5 1327680   // biases -> B3
#define C6 1333824   // zero YBAR
#define C7 1339968   // zero d_out
#define C8 1364544   // zero SE/SX/SY (contiguous, 98304 floats)
__global__ void cvt_all(const float* __restrict__ fc1_w, const float* __restrict__ fc2_w,
                        const float* __restrict__ w3a, const float* __restrict__ w3b,
                        const float* __restrict__ w3c,
                        const float* __restrict__ ba, const float* __restrict__ bb,
                        const float* __restrict__ bc,
                        ushort* __restrict__ W1, ushort* __restrict__ W2,
                        ushort* __restrict__ W3, float* __restrict__ B3,
                        float* __restrict__ ybar_z, float* __restrict__ out_z,
                        float* __restrict__ stats_z)
{
    int i = blockIdx.x * 256 + threadIdx.x;  // float4 index
    float4 z = {0.f, 0.f, 0.f, 0.f};
    if (i < C0)       cvt4(fc1_w, W1, i);
    else if (i < C1)  cvt4(fc2_w, W2, i - C0);
    else if (i < C2)  cvt4(w3a, W3,           i - C1);
    else if (i < C3)  cvt4(w3b, W3 + 589824,  i - C2);
    else if (i < C4)  cvt4(w3c, W3 + 1179648, i - C3);
    else if (i < C5) {
        int j = i - C4;  // 0..575 float4s of B3 (2304 floats)
        const float* src = (j < 192) ? ba : (j < 384) ? bb : bc;
        int off = (j < 192) ? j : (j < 384) ? (j - 192) : (j - 384);
        ((float4*)B3)[j] = ((const float4*)src)[off];
    }
    else if (i < C6)  ((float4*)ybar_z)[i - C5] = z;
    else if (i < C7)  ((float4*)out_z)[i - C6] = z;
    else if (i < C8)  ((float4*)stats_z)[i - C7] = z;
}

// ---------------- GEMM1 variant: A is fp32, converted in-register during staging ------------
// Same 128x128 / BK=64 / XOR-swizzle / XCD-pinned structure as gemm_bt, but A staging is
// global float4 x2 -> f2b -> ds_write_b128 (lane-linear 16B: 2-way bank alias = free).
// A regs for round kt+1 are loaded right after the staging barrier so the fp32 loads are
// in flight during the MFMA block. Eliminates the separate 300MB x-conversion pass.
__global__ __launch_bounds__(256, 2)
void gemm_a32(const float* __restrict__ A, const ushort* __restrict__ Bm,
              const float* __restrict__ bias, ushort* __restrict__ C,
              int M, int N, int K, int relu_ncols)
{
    __shared__ __align__(16) ushort lA[128 * 64];
    __shared__ __align__(16) ushort lB[128 * 64];

    const int tid  = threadIdx.x;
    const int lane = tid & 63, wave = tid >> 6;
    const int wm = wave & 1, wn = wave >> 1;
    const int quad = lane >> 4, r16 = lane & 15;

    const int ntiles = N >> 7;
    const int xcd = blockIdx.x & 7;
    const int j   = blockIdx.x >> 3;
    const int g   = j / ntiles;
    const int n_t = j - g * ntiles;
    const int m_t = xcd + (g << 3);
    const int m0 = m_t * 128, n0 = n_t * 128;

    const int srow = lane >> 2;
    const int scol = ((lane & 3) ^ ((lane >> 3) & 3)) * 8;
    const int goff = (r16 << 5) + ((quad ^ ((r16 >> 1) & 3)) << 3);

    // per-segment fp32 A prefetch registers (4 segments x 8 floats)
    float4 pa[4][2];
#define LOADA(K0)                                                           \
    {                                                                       \
        _Pragma("unroll")                                                   \
        for (int c = 0; c < 4; ++c) {                                       \
            int S = wave * 4 + c; int kh = S >> 3, rs = S & 7;              \
            const float* ga = A + (size_t)(m0 + rs * 16 + srow) * K         \
                              + (K0) + kh * 32 + scol;                      \
            pa[c][0] = ((const float4*)ga)[0];                              \
            pa[c][1] = ((const float4*)ga)[1];                              \
        }                                                                   \
    }

    LOADA(0);
    f32x4 acc[4][4] = {};

    const int kIters = K >> 6;
    for (int kt = 0; kt < kIters; ++kt) {
        __syncthreads();   // previous round's LDS reads complete
        // stage A: convert prefetched fp32 regs -> bf16, lane-linear ds_write_b128
#pragma unroll
        for (int c = 0; c < 4; ++c) {
            int S = wave * 4 + c;
            short8 w;
            w[0] = (short)f2b(pa[c][0].x); w[1] = (short)f2b(pa[c][0].y);
            w[2] = (short)f2b(pa[c][0].z); w[3] = (short)f2b(pa[c][0].w);
            w[4] = (short)f2b(pa[c][1].x); w[5] = (short)f2b(pa[c][1].y);
            w[6] = (short)f2b(pa[c][1].z); w[7] = (short)f2b(pa[c][1].w);
            *(short8*)&lA[S * 512 + lane * 8] = w;
        }
        // stage B via lds-DMA
#pragma unroll
        for (int c = 0; c < 4; ++c) {
            int S = wave * 4 + c; int kh = S >> 3, rs = S & 7;
            const ushort* gb = Bm + (size_t)(n0 + rs * 16 + srow) * K
                               + (kt << 6) + kh * 32 + scol;
            __builtin_amdgcn_global_load_lds(
                (const __attribute__((address_space(1))) void*)gb,
                (__attribute__((address_space(3))) void*)&lB[S * 512], 16, 0, 0);
        }
        if (kt + 1 < kIters) LOADA((kt + 1) << 6);   // fp32 loads fly during MFMA
        __syncthreads();   // staging complete

#pragma unroll
        for (int kh = 0; kh < 2; ++kh) {
            short8 af[4], bf[4];
#pragma unroll
            for (int i = 0; i < 4; ++i)
                af[i] = *(const short8*)&lA[kh * 4096 + (wm * 4 + i) * 512 + goff];
#pragma unroll
            for (int j2 = 0; j2 < 4; ++j2)
                bf[j2] = *(const short8*)&lB[kh * 4096 + (wn * 4 + j2) * 512 + goff];
#pragma unroll
            for (int i = 0; i < 4; ++i)
#pragma unroll
                for (int j2 = 0; j2 < 4; ++j2)
                    acc[i][j2] = __builtin_amdgcn_mfma_f32_16x16x32_bf16(af[i], bf[j2], acc[i][j2], 0, 0, 0);
        }
    }

#pragma unroll
    for (int j2 = 0; j2 < 4; ++j2) {
        int gn = n0 + wn * 64 + j2 * 16 + r16;
        float bv = bias[gn];
        bool dorelu = gn < relu_ncols;
#pragma unroll
        for (int i = 0; i < 4; ++i) {
            int gmb = m0 + wm * 64 + i * 16 + quad * 4;
#pragma unroll
            for (int rr = 0; rr < 4; ++rr) {
                float v = acc[i][j2][rr] + bv;
                if (dorelu) v = fmaxf(v, 0.f);
                C[(size_t)(gmb + rr) * N + gn] = f2b(v);
            }
        }
    }
}

// ---------------- bf16 GEMM (as R8): BK=64, XOR-swizzle staging, XCD-pinned ----------------
// Optional fused row-stats (GEMM3): SE/SX/SY epilogue atomics; e-section C-write SKIPPED
// (nothing reads it once SE is fused).
__global__ __launch_bounds__(256, 2)
void gemm_bt(const ushort* __restrict__ A, const ushort* __restrict__ Bm,
             const float* __restrict__ bias, ushort* __restrict__ C,
             int M, int N, int K, int relu_ncols,
             const float* __restrict__ urw, float* __restrict__ SE,
             float* __restrict__ SX, float* __restrict__ SY)
{
    __shared__ __align__(16) ushort lA[128 * 64];
    __shared__ __align__(16) ushort lB[128 * 64];

    const int tid  = threadIdx.x;
    const int lane = tid & 63, wave = tid >> 6;
    const int wm = wave & 1, wn = wave >> 1;
    const int quad = lane >> 4, r16 = lane & 15;

    const int ntiles = N >> 7;
    const int xcd = blockIdx.x & 7;
    const int j   = blockIdx.x >> 3;
    const int g   = j / ntiles;
    const int n_t = j - g * ntiles;
    const int m_t = xcd + (g << 3);
    const int m0 = m_t * 128, n0 = n_t * 128;

    const int srow = lane >> 2;
    const int scol = ((lane & 3) ^ ((lane >> 3) & 3)) * 8;
    const int goff = (r16 << 5) + ((quad ^ ((r16 >> 1) & 3)) << 3);

    f32x4 acc[4][4] = {};

    const int kIters = K >> 6;
    for (int kt = 0; kt < kIters; ++kt) {
        const int k0 = kt << 6;
        __syncthreads();
#pragma unroll
        for (int c = 0; c < 4; ++c) {
            int S  = wave * 4 + c;
            int kh = S >> 3, rs = S & 7;
            int row = rs * 16 + srow;
            int kc  = k0 + kh * 32 + scol;
            const ushort* ga = A + (size_t)(m0 + row) * K + kc;
            __builtin_amdgcn_global_load_lds(
                (const __attribute__((address_space(1))) void*)ga,
                (__attribute__((address_space(3))) void*)&lA[S * 512], 16, 0, 0);
            const ushort* gb = Bm + (size_t)(n0 + row) * K + kc;
            __builtin_amdgcn_global_load_lds(
                (const __attribute__((address_space(1))) void*)gb,
                (__attribute__((address_space(3))) void*)&lB[S * 512], 16, 0, 0);
        }
        __syncthreads();

#pragma unroll
        for (int kh = 0; kh < 2; ++kh) {
            short8 af[4], bf[4];
#pragma unroll
            for (int i = 0; i < 4; ++i)
                af[i] = *(const short8*)&lA[kh * 4096 + (wm * 4 + i) * 512 + goff];
#pragma unroll
            for (int j2 = 0; j2 < 4; ++j2)
                bf[j2] = *(const short8*)&lB[kh * 4096 + (wn * 4 + j2) * 512 + goff];
#pragma unroll
            for (int i = 0; i < 4; ++i)
#pragma unroll
                for (int j2 = 0; j2 < 4; ++j2)
                    acc[i][j2] = __builtin_amdgcn_mfma_f32_16x16x32_bf16(af[i], bf[j2], acc[i][j2], 0, 0, 0);
        }
    }

    // epilogue: C/D layout col = lane&15, row = quad*4 + reg
    const bool stats = (urw != nullptr);
    const int sec = n0 / DDIM;           // 0=e, 1=xe, 2=ye (GEMM3 only)
    const bool dostore = !(stats && sec == 0);   // skip e-section store
    float st[4][4] = {};
#pragma unroll
    for (int j2 = 0; j2 < 4; ++j2) {
        int gn = n0 + wn * 64 + j2 * 16 + r16;
        float bv = bias[gn];
        bool dorelu = gn < relu_ncols;
        float uw = (stats && sec == 0) ? urw[gn] : 0.f;
#pragma unroll
        for (int i = 0; i < 4; ++i) {
            int gmb = m0 + wm * 64 + i * 16 + quad * 4;
#pragma unroll
            for (int rr = 0; rr < 4; ++rr) {
                float v = acc[i][j2][rr] + bv;
                if (dorelu) v = fmaxf(v, 0.f);
                if (dostore) C[(size_t)(gmb + rr) * N + gn] = f2b(v);
                if (stats) st[i][rr] += (sec == 0) ? v * uw : v * v;
            }
        }
    }
    if (stats) {
#pragma unroll
        for (int i = 0; i < 4; ++i)
#pragma unroll
            for (int rr = 0; rr < 4; ++rr) {
                float v = st[i][rr];
                v += __shfl_xor(v, 1, 64);
                v += __shfl_xor(v, 2, 64);
                v += __shfl_xor(v, 4, 64);
                v += __shfl_xor(v, 8, 64);
                st[i][rr] = v;
            }
        if (r16 == 0) {
            float* dst = (sec == 0) ? SE : (sec == 1) ? SX : SY;
#pragma unroll
            for (int i = 0; i < 4; ++i)
#pragma unroll
                for (int rr = 0; rr < 4; ++rr)
                    atomicAdd(&dst[m0 + wm * 64 + i * 16 + quad * 4 + rr], st[i][rr]);
        }
    }
}

// ---------------- ybar[b,d] += partial over a 32-step s chunk ----------------
__global__ void ybar_k(const ushort* __restrict__ G3, const float* __restrict__ sy,
                       float* __restrict__ ybar)
{
    int b = blockIdx.x, s0 = blockIdx.y * 32;
    int tid = threadIdx.x;
    __shared__ float sr[32];
    if (tid < 32) {
        float v = sy[b * TSEQ + s0 + tid];
        sr[tid] = (1.0f / TSEQ) / fmaxf(sqrtf(v), 1e-12f);
    }
    __syncthreads();
    float a0 = 0.f, a1 = 0.f, a2 = 0.f;
#pragma unroll 8
    for (int s = 0; s < 32; ++s) {
        const ushort* row = G3 + (size_t)(b * TSEQ + s0 + s) * NCAT + 2 * DDIM;
        float w = sr[s];
        a0 += b2f(row[tid])       * w;
        a1 += b2f(row[tid + 256]) * w;
        a2 += b2f(row[tid + 512]) * w;
    }
    atomicAdd(&ybar[b * DDIM + tid],       a0);
    atomicAdd(&ybar[b * DDIM + tid + 256], a1);
    atomicAdd(&ybar[b * DDIM + tid + 512], a2);
}

// ---------------- scores: wave-per-row, 4 rows/block ----------------
__global__ void pw_scores_k(const ushort* __restrict__ G3, const float* __restrict__ ybar,
                            const float* __restrict__ SE, const float* __restrict__ SX,
                            const float* __restrict__ urb, const float* __restrict__ red_w,
                            float* __restrict__ scores)
{
    int wv = threadIdx.x >> 6, lane = threadIdx.x & 63;
    int m = blockIdx.x * 4 + wv;
    int b = m >> 10;
    const ushort* xe = G3 + (size_t)m * NCAT + DDIM;
    const float4* yb = (const float4*)(ybar + b * DDIM);
    float s = 0.f;
#pragma unroll
    for (int c0 = 0; c0 < 3; ++c0) {
        int c = lane + c0 * 64;
        short4v v = *(const short4v*)(xe + c * 4);
        float4 yv = yb[c];
        s += b2f((ushort)v[0]) * yv.x + b2f((ushort)v[1]) * yv.y
           + b2f((ushort)v[2]) * yv.z + b2f((ushort)v[3]) * yv.w;
    }
#pragma unroll
    for (int off = 32; off; off >>= 1) s += __shfl_xor(s, off, 64);
    if (lane == 0) {
        float rnx = 1.f / fmaxf(sqrtf(SX[m]), 1e-12f);
        scores[m] = red_w[0] * (SE[m] + urb[0]) + red_w[1] * (rnx * s);
    }
}

// ---------------- out (with inline softmax): grid (B, 32) ----------------
__global__ void out_sm_k(const ushort* __restrict__ U16, const float* __restrict__ scores,
                         float* __restrict__ out)
{
    int b = blockIdx.x, t0 = blockIdx.y * 32;
    int tid = threadIdx.x;
    int lane = tid & 63, wv = tid >> 6;
    __shared__ float red[8];
    __shared__ float sw[32];

    float v[4];
    float lm = -1e30f;
#pragma unroll
    for (int i = 0; i < 4; ++i) {
        v[i] = scores[b * TSEQ + i * 256 + tid];
        lm = fmaxf(lm, v[i]);
    }
#pragma unroll
    for (int off = 32; off; off >>= 1) lm = fmaxf(lm, __shfl_xor(lm, off, 64));
    if (lane == 0) red[wv] = lm;
    __syncthreads();
    float smax = fmaxf(fmaxf(red[0], red[1]), fmaxf(red[2], red[3]));
    float ls = 0.f;
#pragma unroll
    for (int i = 0; i < 4; ++i) ls += expf(v[i] - smax);
#pragma unroll
    for (int off = 32; off; off >>= 1) ls += __shfl_xor(ls, off, 64);
    if (lane == 0) red[4 + wv] = ls;
    __syncthreads();
    float inv = 1.f / (red[4] + red[5] + red[6] + red[7]);

    if (tid < 32) sw[tid] = expf(scores[b * TSEQ + t0 + tid] - smax) * inv;
    __syncthreads();

    float a0 = 0.f, a1 = 0.f, a2 = 0.f;
#pragma unroll 8
    for (int t = 0; t < 32; ++t) {
        const ushort* row = U16 + (size_t)(b * TSEQ + t0 + t) * DDIM;
        float w = sw[t];
        a0 += b2f(row[tid])       * w;
        a1 += b2f(row[tid + 256]) * w;
        a2 += b2f(row[tid + 512]) * w;
    }
    atomicAdd(&out[b * DDIM + tid],       a0);
    atomicAdd(&out[b * DDIM + tid + 256], a1);
    atomicAdd(&out[b * DDIM + tid + 512], a2);
}

// ---------------- workspace layout (bytes) ----------------
// X16 eliminated (GEMM1 reads fp32 x directly). G3 aliases [0,151MB); H16 at 100MB is
// dead before GEMM3 writes G3 (same overlap discipline as before).
static const size_t O_H16   = 100663296;    // 100663296
static const size_t O_G3    = 0;            // 150994944 (alias over [0, H16-end))
static const size_t O_U16   = 201326592;    // 50331648
static const size_t O_W1    = 251658240;    // 4718592
static const size_t O_W2    = 256376832;    // 2359296
static const size_t O_W3    = 258736128;    // 3538944
static const size_t O_B3    = 262275072;    // 9216
static const size_t O_SE    = 262284288;    // 131072  (SE/SX/SY contiguous)
static const size_t O_SX    = 262415360;    // 131072
static const size_t O_SY    = 262546432;    // 131072
static const size_t O_SCORE = 262677504;    // 131072
static const size_t O_YBAR  = 262939648;    // 98304
// total: 263037952 bytes (~263 MB)

extern "C" void kernel_launch(void* const* d_in, const int* in_sizes, int n_in,
                              void* d_out, int out_size, void* d_ws, size_t ws_size,
                              hipStream_t stream)
{
    const float* x        = (const float*)d_in[0];
    const float* fc1_w    = (const float*)d_in[1];
    const float* fc1_b    = (const float*)d_in[2];
    const float* fc2_w    = (const float*)d_in[3];
    const float* fc2_b    = (const float*)d_in[4];
    const float* un_emb_w = (const float*)d_in[5];
    const float* un_emb_b = (const float*)d_in[6];
    const float* un_red_w = (const float*)d_in[7];
    const float* un_red_b = (const float*)d_in[8];
    const float* pw_x_w   = (const float*)d_in[9];
    const float* pw_x_b   = (const float*)d_in[10];
    const float* pw_y_w   = (const float*)d_in[11];
    const float* pw_y_b   = (const float*)d_in[12];
    const float* red_w    = (const float*)d_in[13];

    char* ws = (char*)d_ws;
    ushort* H16 = (ushort*)(ws + O_H16);
    ushort* G3  = (ushort*)(ws + O_G3);
    ushort* U16 = (ushort*)(ws + O_U16);
    ushort* W1  = (ushort*)(ws + O_W1);
    ushort* W2  = (ushort*)(ws + O_W2);
    ushort* W3  = (ushort*)(ws + O_W3);
    float*  B3  = (float*)(ws + O_B3);
    float*  SE  = (float*)(ws + O_SE);
    float*  SX  = (float*)(ws + O_SX);
    float*  SY  = (float*)(ws + O_SY);
    float*  SCORES = (float*)(ws + O_SCORE);
    float*  YBAR = (float*)(ws + O_YBAR);

    // --- weights/bias conversion + zero-init (x no longer converted) ---
    cvt_all<<<5331, 256, 0, stream>>>(fc1_w, fc2_w, un_emb_w, pw_x_w, pw_y_w,
                                      un_emb_b, pw_x_b, pw_y_b,
                                      W1, W2, W3, B3, YBAR, (float*)d_out, SE);

    // --- GEMM chain ---
    // h = relu(x @ fc1_w^T + fc1_b)  — A fp32, converted in staging
    gemm_a32<<<(MROWS / 128) * (INDIM / 128), 256, 0, stream>>>(
        x, W1, fc1_b, H16, MROWS, INDIM, INDIM, INDIM);
    // u = h @ fc2_w^T + fc2_b
    gemm_bt<<<(MROWS / 128) * (DDIM / 128), 256, 0, stream>>>(
        H16, W2, fc2_b, U16, MROWS, DDIM, INDIM, 0,
        nullptr, nullptr, nullptr, nullptr);
    // [e|xe|ye] = u @ W3^T + B3; relu+SE on e (not stored), SX/SY fused
    gemm_bt<<<(MROWS / 128) * (NCAT / 128), 256, 0, stream>>>(
        U16, W3, B3, G3, MROWS, NCAT, DDIM, DDIM,
        un_red_w, SE, SX, SY);

    // --- tail ---
    ybar_k<<<dim3(BBATCH, 32), 256, 0, stream>>>(G3, SY, YBAR);
    pw_scores_k<<<MROWS / 4, 256, 0, stream>>>(G3, YBAR, SE, SX, un_red_b, red_w, SCORES);
    out_sm_k<<<dim3(BBATCH, 32), 256, 0, stream>>>(U16, SCORES, (float*)d_out);
}